// Round 3
// baseline (225.657 us; speedup 1.0000x reference)
//
#include <hip/hip_runtime.h>
#include <cstdint>
#include <cstddef>

#define NN 2048
#define BB 8
// thr = 0.5 + MARGIN_PUSH
#define THR 0.6f
#define PUSH_BLOCKS 1024

// ws layout (floats unless noted). Every consumed slot is produced in the
// same launch (k1 writes the zeros k2's atomics need), so the harness's
// 0xAA re-poison never leaks.
//   [0 .. 16383]          s = sigmoid(lof_tag_avg_img)  (64 KB)
//   [16384 .. 16447]      pnum[64]  pull numerator partials (k1 blocks)
//   [16448 .. 16511]      pden[64]  pull denominator partials
//   [16512]               push sum accumulator   (float, atomicAdd)
//   [16513] (uint)        push count accumulator (exact int, atomicAdd)
//   [16514] (uint)        completion counter for last-block-done

#define OFF_S     0
#define OFF_PNUM  16384
#define OFF_PDEN  16448
#define OFF_ASUM  16512
#define OFF_ACNT  16513
#define OFF_CTR   16514

__device__ __forceinline__ float sigmoidf(float x) {
    return 1.0f / (1.0f + expf(-x));
}

// Kernel 1: s = sigmoid(avg); pull partials; zero k2's accumulators.
// 64 blocks x 256.
__global__ __launch_bounds__(256)
void k_sig_pull(const float* __restrict__ x,      // lof_tag_img
                const float* __restrict__ avg,    // lof_tag_avg_img
                const float* __restrict__ gat,    // lof_tag_avg_gather_img
                const float* __restrict__ cent,   // centerness_img
                float* __restrict__ ws) {
    int idx = blockIdx.x * 256 + threadIdx.x;   // exactly 16384 threads

    if (idx == 0) {
        ws[OFF_ASUM] = 0.0f;
        ((unsigned int*)ws)[OFF_ACNT] = 0u;
        ((unsigned int*)ws)[OFF_CTR]  = 0u;
        // visible to k2 via the dispatch boundary (release at kernel end)
    }

    float a = avg[idx];
    ws[OFF_S + idx] = sigmoidf(a);

    float g  = gat[idx];
    float xv = x[idx];
    float c  = cent[idx];
    // target = round(sigmoid(g)) -> 1 iff sigmoid(g) > 0.5
    float target = (sigmoidf(g) > 0.5f) ? 1.0f : 0.0f;
    // stable softplus
    float sp = fmaxf(xv, 0.0f) + log1pf(expf(-fabsf(xv)));
    float tag = sp - xv * target;
    float num = tag * c;
    float den = c;

    #pragma unroll
    for (int off = 32; off; off >>= 1) {
        num += __shfl_down(num, off);
        den += __shfl_down(den, off);
    }
    __shared__ float snum[4], sden[4];
    int wave = threadIdx.x >> 6, lane = threadIdx.x & 63;
    if (lane == 0) { snum[wave] = num; sden[wave] = den; }
    __syncthreads();
    if (threadIdx.x == 0) {
        float tn = 0.f, td = 0.f;
        #pragma unroll
        for (int w = 0; w < 4; w++) { tn += snum[w]; td += sden[w]; }
        ws[OFF_PNUM + blockIdx.x] = tn;
        ws[OFF_PDEN + blockIdx.x] = td;
    }
}

// Kernel 2: push term + final reduce (last-block-done).
// One thread owns (i, 16 consecutive j's, all 8 batches).
// 2048 * 128 = 262144 threads = 1024 blocks * 256. Mask reads: uint4,
// fully coalesced — at the 33.5 MB mask-read roofline.
__global__ __launch_bounds__(256)
void k_push(const uint8_t* __restrict__ mask,
            float* __restrict__ ws,
            float* __restrict__ out) {
    const float* s = ws + OFF_S;
    int tid = blockIdx.x * 256 + threadIdx.x;
    int i  = tid >> 7;                 // 0..2047
    int j0 = (tid & 127) << 4;         // 0,16,...,2032

    float si[BB];
    #pragma unroll
    for (int b = 0; b < BB; b++) si[b] = s[b * NN + i];   // wave-uniform

    uint4 mk[BB];
    const uint4* m4 = reinterpret_cast<const uint4*>(mask);
    #pragma unroll
    for (int b = 0; b < BB; b++) {
        int u4idx = b * (NN * NN / 16) + i * (NN / 16) + (j0 >> 4);
        mk[b] = m4[u4idx];
    }

    float fsum = 0.f;
    unsigned int fcnt = 0u;

    for (int c = 0; c < 4; c++) {
        float4 sj[BB];
        #pragma unroll
        for (int b = 0; b < BB; b++) {
            sj[b] = reinterpret_cast<const float4*>(s + b * NN + j0)[c];
        }
        unsigned int mw[BB];
        #pragma unroll
        for (int b = 0; b < BB; b++) mw[b] = ((const unsigned int*)&mk[b])[c];

        #pragma unroll
        for (int k = 0; k < 4; k++) {
            bool neq = false;
            float lsum = 0.f;
            unsigned int lcnt = 0u;
            #pragma unroll
            for (int b = 0; b < BB; b++) {
                float sjv = ((const float*)&sj[b])[k];
                float d = fabsf(sjv - si[b]);
                neq = neq || (d != 0.0f);
                unsigned int mb = (mw[b] >> (8 * k)) & 0xffu;   // 0 or 1
                lcnt += mb;
                lsum += mb ? (THR - d) : 0.0f;
            }
            // dist_mask[i,j]: any b with s[b,i] != s[b,j]
            if (neq) { fcnt += lcnt; fsum += lsum; }
        }
    }

    // block reduction
    #pragma unroll
    for (int off = 32; off; off >>= 1) {
        fsum += __shfl_down(fsum, off);
        fcnt += __shfl_down(fcnt, off);
    }
    __shared__ float ssum[4];
    __shared__ unsigned int scnt[4];
    __shared__ int is_last;
    int wave = threadIdx.x >> 6, lane = threadIdx.x & 63;
    if (lane == 0) { ssum[wave] = fsum; scnt[wave] = fcnt; }
    __syncthreads();
    if (threadIdx.x == 0) {
        float ts = 0.f; unsigned int tc = 0u;
        #pragma unroll
        for (int w = 0; w < 4; w++) { ts += ssum[w]; tc += scnt[w]; }
        // device-scope atomics: coherent across XCDs
        atomicAdd(&ws[OFF_ASUM], ts);
        atomicAdd(&((unsigned int*)ws)[OFF_ACNT], tc);
        __threadfence();   // data atomics complete before the counter bump
        unsigned int old = atomicAdd(&((unsigned int*)ws)[OFF_CTR], 1u);
        is_last = (old == PUSH_BLOCKS - 1) ? 1 : 0;
    }
    __syncthreads();

    if (is_last) {
        // all other blocks' data atomics are visible (counter is the release)
        int t = threadIdx.x;
        float num = 0.f, den = 0.f;
        if (t < 64) { num = ws[OFF_PNUM + t]; den = ws[OFF_PDEN + t]; }
        if (t < 64) {
            #pragma unroll
            for (int off = 32; off; off >>= 1) {
                num += __shfl_down(num, off);
                den += __shfl_down(den, off);
            }
        }
        if (t == 0) {
            float ps = atomicAdd(&ws[OFF_ASUM], 0.0f);                 // coherent read
            unsigned int pc = atomicAdd(&((unsigned int*)ws)[OFF_ACNT], 0u);
            out[0] = num / den;                                // PULL_FACTOR = 1
            out[1] = (pc > 0u) ? (ps / (float)pc) : 0.0f;      // PUSH_FACTOR = 1
        }
    }
}

extern "C" void kernel_launch(void* const* d_in, const int* in_sizes, int n_in,
                              void* d_out, int out_size, void* d_ws, size_t ws_size,
                              hipStream_t stream) {
    const float*   x    = (const float*)d_in[0];   // lof_tag_img
    const float*   avg  = (const float*)d_in[1];   // lof_tag_avg_img
    const float*   gat  = (const float*)d_in[2];   // lof_tag_avg_gather_img
    const uint8_t* mask = (const uint8_t*)d_in[3]; // mask (bool bytes)
    const float*   cent = (const float*)d_in[4];   // centerness_img
    float* out = (float*)d_out;
    float* ws  = (float*)d_ws;

    // 2-node graph: k1 produces s + pull partials + zeroed accumulators;
    // k2 does push and the final reduce via last-block-done.
    k_sig_pull<<<(BB * NN) / 256, 256, 0, stream>>>(x, avg, gat, cent, ws);
    k_push<<<PUSH_BLOCKS, 256, 0, stream>>>(mask, ws, out);
}

// Round 4
// 186.366 us; speedup vs baseline: 1.2108x; 1.2108x over previous
//
#include <hip/hip_runtime.h>
#include <cstdint>
#include <cstddef>

#define NN 2048
#define BB 8
// thr = 0.5 + MARGIN_PUSH
#define THR 0.6f

// ws layout (all floats unless noted; every slot is written every launch,
// so the harness's 0xAA poison never leaks):
//   [0 .. 16383]            s = sigmoid(lof_tag_avg_img)   (64 KB)
//   [16384 .. 16447]        pnum[64]   pull numerator partials (per block of k1)
//   [16448 .. 16511]        pden[64]   pull denominator partials
//   [16512 .. 17535]        psum[1024] push sum partials (per block of k2)
//   [17536 .. 18559] (uint) pcnt[1024] push count partials (exact int)

#define OFF_S     0
#define OFF_PNUM  16384
#define OFF_PDEN  16448
#define OFF_PSUM  16512
#define OFF_PCNT  17536

__device__ __forceinline__ float sigmoidf(float x) {
    return 1.0f / (1.0f + expf(-x));
}

// Kernel 1: s = sigmoid(avg); pull partial sums (64 blocks x 256).
__global__ __launch_bounds__(256)
void k_sig_pull(const float* __restrict__ x,      // lof_tag_img
                const float* __restrict__ avg,    // lof_tag_avg_img
                const float* __restrict__ gat,    // lof_tag_avg_gather_img
                const float* __restrict__ cent,   // centerness_img
                float* __restrict__ ws) {
    int idx = blockIdx.x * 256 + threadIdx.x;   // exactly 16384 threads

    float a = avg[idx];
    ws[OFF_S + idx] = sigmoidf(a);

    float g  = gat[idx];
    float xv = x[idx];
    float c  = cent[idx];
    // target = round(sigmoid(g)) -> 1 iff sigmoid(g) > 0.5
    float target = (sigmoidf(g) > 0.5f) ? 1.0f : 0.0f;
    // stable softplus
    float sp = fmaxf(xv, 0.0f) + log1pf(expf(-fabsf(xv)));
    float tag = sp - xv * target;
    float num = tag * c;
    float den = c;

    // block reduction (wave shuffle then LDS across the 4 waves)
    #pragma unroll
    for (int off = 32; off; off >>= 1) {
        num += __shfl_down(num, off);
        den += __shfl_down(den, off);
    }
    __shared__ float snum[4], sden[4];
    int wave = threadIdx.x >> 6, lane = threadIdx.x & 63;
    if (lane == 0) { snum[wave] = num; sden[wave] = den; }
    __syncthreads();
    if (threadIdx.x == 0) {
        float tn = 0.f, td = 0.f;
        #pragma unroll
        for (int w = 0; w < 4; w++) { tn += snum[w]; td += sden[w]; }
        ws[OFF_PNUM + blockIdx.x] = tn;
        ws[OFF_PDEN + blockIdx.x] = td;
    }
}

// Kernel 2: push term. One thread owns (i, 16 consecutive j's, all 8 batches).
// 2048 * 128 = 262144 threads = 1024 blocks * 256. Mask reads: uint4, fully
// coalesced (1 KB/wave/instr) — this kernel is at the 33.5 MB mask roofline.
__global__ __launch_bounds__(256)
void k_push(const uint8_t* __restrict__ mask,
            float* __restrict__ ws) {
    const float* s = ws + OFF_S;
    int tid = blockIdx.x * 256 + threadIdx.x;
    int i  = tid >> 7;                 // 0..2047
    int j0 = (tid & 127) << 4;         // 0,16,...,2032

    float si[BB];
    #pragma unroll
    for (int b = 0; b < BB; b++) si[b] = s[b * NN + i];   // wave-broadcast

    // 16 mask bytes per batch, coalesced uint4 loads
    uint4 mk[BB];
    const uint4* m4 = reinterpret_cast<const uint4*>(mask);
    #pragma unroll
    for (int b = 0; b < BB; b++) {
        int u4idx = b * (NN * NN / 16) + i * (NN / 16) + (j0 >> 4);
        mk[b] = m4[u4idx];
    }

    float fsum = 0.f;
    unsigned int fcnt = 0u;

    for (int c = 0; c < 4; c++) {
        float4 sj[BB];
        #pragma unroll
        for (int b = 0; b < BB; b++) {
            sj[b] = reinterpret_cast<const float4*>(s + b * NN + j0)[c];
        }
        unsigned int mw[BB];
        #pragma unroll
        for (int b = 0; b < BB; b++) mw[b] = ((const unsigned int*)&mk[b])[c];

        #pragma unroll
        for (int k = 0; k < 4; k++) {
            bool neq = false;
            float lsum = 0.f;
            unsigned int lcnt = 0u;
            #pragma unroll
            for (int b = 0; b < BB; b++) {
                float sjv = ((const float*)&sj[b])[k];
                float d = fabsf(sjv - si[b]);
                neq = neq || (d != 0.0f);
                unsigned int mb = (mw[b] >> (8 * k)) & 0xffu;   // 0 or 1
                lcnt += mb;
                lsum += mb ? (THR - d) : 0.0f;
            }
            // dist_mask[i,j]: any b with s[b,i] != s[b,j]; wraps the whole row
            if (neq) { fcnt += lcnt; fsum += lsum; }
        }
    }

    // block reduction
    #pragma unroll
    for (int off = 32; off; off >>= 1) {
        fsum += __shfl_down(fsum, off);
        fcnt += __shfl_down(fcnt, off);
    }
    __shared__ float ssum[4];
    __shared__ unsigned int scnt[4];
    int wave = threadIdx.x >> 6, lane = threadIdx.x & 63;
    if (lane == 0) { ssum[wave] = fsum; scnt[wave] = fcnt; }
    __syncthreads();
    if (threadIdx.x == 0) {
        float ts = 0.f; unsigned int tc = 0u;
        #pragma unroll
        for (int w = 0; w < 4; w++) { ts += ssum[w]; tc += scnt[w]; }
        ws[OFF_PSUM + blockIdx.x] = ts;
        ((unsigned int*)ws)[OFF_PCNT + blockIdx.x] = tc;
    }
}

// Kernel 3: reduce all partials, write the two output scalars. 1 block x 256.
__global__ __launch_bounds__(256)
void k_final(const float* __restrict__ ws, float* __restrict__ out) {
    int tid = threadIdx.x;

    float num = 0.f, den = 0.f;
    if (tid < 64) { num = ws[OFF_PNUM + tid]; den = ws[OFF_PDEN + tid]; }

    float ps = 0.f;
    unsigned int pc = 0u;
    #pragma unroll
    for (int r = 0; r < 4; r++) {
        int idx = tid + r * 256;
        ps += ws[OFF_PSUM + idx];
        pc += ((const unsigned int*)ws)[OFF_PCNT + idx];
    }

    #pragma unroll
    for (int off = 32; off; off >>= 1) {
        num += __shfl_down(num, off);
        den += __shfl_down(den, off);
        ps  += __shfl_down(ps, off);
        pc  += __shfl_down(pc, off);
    }
    __shared__ float snum[4], sden[4], ssum[4];
    __shared__ unsigned int scnt[4];
    int wave = tid >> 6, lane = tid & 63;
    if (lane == 0) { snum[wave] = num; sden[wave] = den; ssum[wave] = ps; scnt[wave] = pc; }
    __syncthreads();
    if (tid == 0) {
        float tn = 0.f, td = 0.f, ts = 0.f;
        unsigned int tc = 0u;
        #pragma unroll
        for (int w = 0; w < 4; w++) { tn += snum[w]; td += sden[w]; ts += ssum[w]; tc += scnt[w]; }
        out[0] = tn / td;                                   // PULL_FACTOR = 1
        out[1] = (tc > 0u) ? (ts / (float)tc) : 0.0f;       // PUSH_FACTOR = 1
    }
}

extern "C" void kernel_launch(void* const* d_in, const int* in_sizes, int n_in,
                              void* d_out, int out_size, void* d_ws, size_t ws_size,
                              hipStream_t stream) {
    const float*   x    = (const float*)d_in[0];   // lof_tag_img
    const float*   avg  = (const float*)d_in[1];   // lof_tag_avg_img
    const float*   gat  = (const float*)d_in[2];   // lof_tag_avg_gather_img
    const uint8_t* mask = (const uint8_t*)d_in[3]; // mask (bool bytes)
    const float*   cent = (const float*)d_in[4];   // centerness_img
    float* out = (float*)d_out;
    float* ws  = (float*)d_ws;

    // 3-node graph, no atomics, no initialization required (every ws slot
    // consumed is produced in the same launch).
    k_sig_pull<<<(BB * NN) / 256, 256, 0, stream>>>(x, avg, gat, cent, ws);
    k_push<<<(NN * (NN / 16)) / 256, 256, 0, stream>>>(mask, ws);
    k_final<<<1, 256, 0, stream>>>(ws, out);
}